// Round 4
// baseline (312.127 us; speedup 1.0000x reference)
//
#include <hip/hip_runtime.h>
#include <hip/hip_bf16.h>

#define S 64
#define B 32
#define HID 16
#define EMB 32
#define V 50257
#define NCB 197                 // column blocks of 256 cols
#define VP2 (NCB*256)           // 50432 padded cols
#define M 2048                  // S*B rows
#define PREP_BLOCKS (VP2*EMB/256)   // 6304 exactly
#define NRG 4                   // row groups (blocks in y)
#define RT_PER (128/NRG)        // 32 row-tiles per block

using bf16x8 = __attribute__((ext_vector_type(8))) __bf16;
using f32x4  = __attribute__((ext_vector_type(4))) float;

// ---------------- K1: fused prep ---------------------------------------------------
__global__ void k_prep(const float* __restrict__ W_ho, const float* __restrict__ b_ho,
                       const int* __restrict__ idx, const float* __restrict__ emb,
                       const float* __restrict__ W_lr, const float* __restrict__ b_lr,
                       const float* __restrict__ W_rl, const float* __restrict__ b_rl,
                       __bf16* __restrict__ Wb, float* __restrict__ bias,
                       float* __restrict__ P) {
    const int bx = blockIdx.x;
    if (bx < PREP_BLOCKS) {
        int i = bx * 256 + threadIdx.x;          // < VP2*EMB exactly
        if (i < VP2) bias[i] = (i < V) ? b_ho[i] : -1e30f;
        int v = i >> 5;
        Wb[i] = (v < V) ? (__bf16)W_ho[i] : (__bf16)0.f;
    } else {
        int i = (bx - PREP_BLOCKS) * 256 + threadIdx.x;   // 0..65535
        const int dir = i >> 15, r = i & 32767, m = r >> 4, j = r & 15;
        const float* W  = dir ? W_rl : W_lr;
        const float* bb = dir ? b_rl : b_lr;
        const int tok = idx[m];
        const float4* er = reinterpret_cast<const float4*>(emb + (size_t)tok * EMB);
        const float4* wr = reinterpret_cast<const float4*>(W + j * (EMB + HID));
        float acc = bb[j];
        #pragma unroll
        for (int q = 0; q < 8; ++q) {
            float4 e4 = er[q], w4 = wr[q];
            acc += e4.x * w4.x + e4.y * w4.y + e4.z * w4.z + e4.w * w4.w;
        }
        P[i] = acc;
    }
}

// ---------------- K2: serial RNN scans (single-wave blocks, NO barriers) -----------
__global__ void k_rnn(const float* __restrict__ P,
                      const float* __restrict__ W_lr, const float* __restrict__ W_rl,
                      const float* __restrict__ h0, __bf16* __restrict__ hcat) {
    __shared__ float Psh[S * 4 * HID];   // 16 KB: [s][bl][j]
    __shared__ float hsh[4][17];
    const int t = threadIdx.x;
    const int dir = blockIdx.x >> 3, bq = blockIdx.x & 7;
    const int bl = t >> 4, j = t & 15;
    const int b = bq * 4 + bl;
    {
        const float4* Pg4 = reinterpret_cast<const float4*>(P);
        float4* Ps4 = reinterpret_cast<float4*>(Psh);
        #pragma unroll
        for (int i = 0; i < 16; ++i) {
            int s = (t >> 4) + 4 * i;
            Ps4[t + 64 * i] = Pg4[dir * 8192 + s * 128 + bq * 16 + (t & 15)];
        }
    }
    const float* Wd = (dir ? W_rl : W_lr) + j * (EMB + HID) + EMB;
    float wh[16];
    #pragma unroll
    for (int q = 0; q < 4; ++q) {
        float4 w4 = *reinterpret_cast<const float4*>(Wd + q * 4);
        wh[q * 4 + 0] = w4.x; wh[q * 4 + 1] = w4.y;
        wh[q * 4 + 2] = w4.z; wh[q * 4 + 3] = w4.w;
    }
    float hcur = h0[j];
    hsh[bl][j] = hcur;
    for (int step = 0; step < S; ++step) {
        const int s = dir ? (S - 1 - step) : step;
        hcat[(s * B + b) * 32 + dir * HID + j] = (__bf16)hcur;   // pre-state
        float acc = Psh[s * 64 + bl * 16 + j];
        #pragma unroll
        for (int k = 0; k < HID; ++k) acc += wh[k] * hsh[bl][k];
        hcur = tanhf(acc);
        hsh[bl][j] = hcur;
    }
}

// ---------------- K3: pass 1 — Wb slice in registers, loop over row-tiles ----------
__global__ void k_pass1(const __bf16* __restrict__ hb, const __bf16* __restrict__ Wb,
                        const float* __restrict__ bias, float* __restrict__ partials) {
    const int cbx = blockIdx.x, rg = blockIdx.y;
    const int wave = threadIdx.x >> 6, lane = threadIdx.x & 63;
    const int lr = lane & 15, kg = lane >> 4;
    const int ttbase = cbx * 16 + wave * 4;
    bf16x8 wfrag[4]; float bc[4];
    #pragma unroll
    for (int q = 0; q < 4; ++q) {
        wfrag[q] = *reinterpret_cast<const bf16x8*>(Wb + ((ttbase + q) * 16 + lr) * 32 + kg * 8);
        bc[q] = bias[(ttbase + q) * 16 + lr];
    }
    __shared__ float red[4][16];
    const f32x4 zero = {0.f, 0.f, 0.f, 0.f};
    for (int rt = rg * RT_PER; rt < rg * RT_PER + RT_PER; ++rt) {
        const int m0 = rt * 16;
        const bf16x8 a = *reinterpret_cast<const bf16x8*>(hb + (m0 + lr) * 32 + kg * 8);
        float s0 = 0.f, s1 = 0.f, s2 = 0.f, s3 = 0.f;
        #pragma unroll
        for (int q = 0; q < 4; ++q) {
            f32x4 d = __builtin_amdgcn_mfma_f32_16x16x32_bf16(a, wfrag[q], zero, 0, 0, 0);
            s0 += __expf(d[0] + bc[q]);
            s1 += __expf(d[1] + bc[q]);
            s2 += __expf(d[2] + bc[q]);
            s3 += __expf(d[3] + bc[q]);
        }
        #pragma unroll
        for (int off = 1; off < 16; off <<= 1) {
            s0 += __shfl_xor(s0, off);
            s1 += __shfl_xor(s1, off);
            s2 += __shfl_xor(s2, off);
            s3 += __shfl_xor(s3, off);
        }
        if (lr == 0) {
            red[wave][kg * 4 + 0] = s0;
            red[wave][kg * 4 + 1] = s1;
            red[wave][kg * 4 + 2] = s2;
            red[wave][kg * 4 + 3] = s3;
        }
        __syncthreads();
        if (threadIdx.x < 16)
            partials[cbx * M + m0 + threadIdx.x] =
                red[0][threadIdx.x] + red[1][threadIdx.x] +
                red[2][threadIdx.x] + red[3][threadIdx.x];
        __syncthreads();
    }
}

// ---------------- K4: reduce partials -> logZ per row ------------------------------
__global__ void k_reduce(const float* __restrict__ partials, float* __restrict__ logZ) {
    int r = blockIdx.x * 256 + threadIdx.x;
    float tot = 0.f;
    for (int c = 0; c < NCB; ++c) tot += partials[c * M + r];
    logZ[r] = logf(tot);
}

// ---------------- K5: pass 2 — PROBE: row-tile loop executed TWICE -----------------
// Idempotent rewrite of identical values; T_total - T_R3 isolates T_pass2.
__global__ void k_pass2(const __bf16* __restrict__ hb, const __bf16* __restrict__ Wb,
                        const float* __restrict__ bias, const float* __restrict__ logZ,
                        float* __restrict__ out) {
    __shared__ float stage[16][260];
    const int cbx = blockIdx.x, rg = blockIdx.y;
    const int wave = threadIdx.x >> 6, lane = threadIdx.x & 63;
    const int lr = lane & 15, kg = lane >> 4;
    const int ttbase = cbx * 16 + wave * 4;
    bf16x8 wfrag[4]; float bc[4];
    #pragma unroll
    for (int q = 0; q < 4; ++q) {
        wfrag[q] = *reinterpret_cast<const bf16x8*>(Wb + ((ttbase + q) * 16 + lr) * 32 + kg * 8);
        bc[q] = bias[(ttbase + q) * 16 + lr];
    }
    const int cb = cbx * 256;
    const f32x4 zero = {0.f, 0.f, 0.f, 0.f};
    for (int rep = 0; rep < 2; ++rep) {
        for (int rt = rg * RT_PER; rt < rg * RT_PER + RT_PER; ++rt) {
            const int m0 = rt * 16;
            const bf16x8 a = *reinterpret_cast<const bf16x8*>(hb + (m0 + lr) * 32 + kg * 8);
            #pragma unroll
            for (int q = 0; q < 4; ++q) {
                f32x4 d = __builtin_amdgcn_mfma_f32_16x16x32_bf16(a, wfrag[q], zero, 0, 0, 0);
                const int cl = wave * 64 + q * 16 + lr;
                #pragma unroll
                for (int r = 0; r < 4; ++r)
                    stage[kg * 4 + r][cl] = d[r] + bc[q];
            }
            asm volatile("s_waitcnt lgkmcnt(0)" ::: "memory");
            __builtin_amdgcn_s_barrier();
            __builtin_amdgcn_sched_barrier(0);
            #pragma unroll
            for (int r = 0; r < 4; ++r) {
                const int row = wave * 4 + r;
                const float lz = logZ[m0 + row];
                const size_t R = (size_t)(m0 + row) * V;
                #pragma unroll
                for (int it = 0; it < 4; ++it) {
                    const int c = it * 64 + lane;
                    const int col = cb + c;
                    if (col < V) out[R + col] = stage[row][c] - lz;
                }
            }
            asm volatile("s_waitcnt lgkmcnt(0)" ::: "memory");
            __builtin_amdgcn_s_barrier();
            __builtin_amdgcn_sched_barrier(0);
        }
    }
}

extern "C" void kernel_launch(void* const* d_in, const int* in_sizes, int n_in,
                              void* d_out, int out_size, void* d_ws, size_t ws_size,
                              hipStream_t stream) {
    const int*   idx       = (const int*)d_in[0];
    const float* embedding = (const float*)d_in[1];
    const float* W_lr      = (const float*)d_in[2];
    const float* b_lr      = (const float*)d_in[3];
    const float* W_rl      = (const float*)d_in[4];
    const float* b_rl      = (const float*)d_in[5];
    const float* W_ho      = (const float*)d_in[6];
    const float* b_ho      = (const float*)d_in[7];
    const float* h0        = (const float*)d_in[8];
    float* out = (float*)d_out;

    char* ws = (char*)d_ws;
    size_t off = 0;
    __bf16* Wb      = (__bf16*)(ws + off); off += (size_t)VP2 * EMB * 2;   // 3,227,648
    float*  bias    = (float*)(ws + off);  off += (size_t)VP2 * 4;         //   201,728
    __bf16* hb      = (__bf16*)(ws + off); off += (size_t)M * 32 * 2;      //   131,072
    float*  P       = (float*)(ws + off);  off += (size_t)2 * M * HID * 4; //   262,144
    float*  partials= (float*)(ws + off);  off += (size_t)NCB * M * 4;     // 1,613,824
    float*  logZ    = (float*)(ws + off);  off += (size_t)M * 4;           //     8,192

    k_prep<<<PREP_BLOCKS + 256, 256, 0, stream>>>(W_ho, b_ho, idx, embedding,
                                                  W_lr, b_lr, W_rl, b_rl, Wb, bias, P);
    k_rnn<<<16, 64, 0, stream>>>(P, W_lr, W_rl, h0, hb);
    k_pass1<<<dim3(NCB, NRG), 256, 0, stream>>>(hb, Wb, bias, partials);
    k_reduce<<<8, 256, 0, stream>>>(partials, logZ);
    k_pass2<<<dim3(NCB, NRG), 256, 0, stream>>>(hb, Wb, bias, logZ, out);
}

// Round 5
// 293.094 us; speedup vs baseline: 1.0649x; 1.0649x over previous
//
#include <hip/hip_runtime.h>
#include <hip/hip_bf16.h>

#define S 64
#define B 32
#define HID 16
#define EMB 32
#define V 50257
#define NCB 197                 // column blocks of 256 cols
#define VP2 (NCB*256)           // 50432 padded cols
#define M 2048                  // S*B rows
#define PREP_BLOCKS (VP2*EMB/256)   // 6304 exactly
#define NRG 4                   // row groups for pass1 only
#define RT_PER (128/NRG)

using bf16x8 = __attribute__((ext_vector_type(8))) __bf16;
using f32x4  = __attribute__((ext_vector_type(4))) float;

// ---------------- K1: fused prep ---------------------------------------------------
__global__ void k_prep(const float* __restrict__ W_ho, const float* __restrict__ b_ho,
                       const int* __restrict__ idx, const float* __restrict__ emb,
                       const float* __restrict__ W_lr, const float* __restrict__ b_lr,
                       const float* __restrict__ W_rl, const float* __restrict__ b_rl,
                       __bf16* __restrict__ Wb, float* __restrict__ bias,
                       float* __restrict__ P) {
    const int bx = blockIdx.x;
    if (bx < PREP_BLOCKS) {
        int i = bx * 256 + threadIdx.x;          // < VP2*EMB exactly
        if (i < VP2) bias[i] = (i < V) ? b_ho[i] : -1e30f;
        int v = i >> 5;
        Wb[i] = (v < V) ? (__bf16)W_ho[i] : (__bf16)0.f;
    } else {
        int i = (bx - PREP_BLOCKS) * 256 + threadIdx.x;   // 0..65535
        const int dir = i >> 15, r = i & 32767, m = r >> 4, j = r & 15;
        const float* W  = dir ? W_rl : W_lr;
        const float* bb = dir ? b_rl : b_lr;
        const int tok = idx[m];
        const float4* er = reinterpret_cast<const float4*>(emb + (size_t)tok * EMB);
        const float4* wr = reinterpret_cast<const float4*>(W + j * (EMB + HID));
        float acc = bb[j];
        #pragma unroll
        for (int q = 0; q < 8; ++q) {
            float4 e4 = er[q], w4 = wr[q];
            acc += e4.x * w4.x + e4.y * w4.y + e4.z * w4.z + e4.w * w4.w;
        }
        P[i] = acc;
    }
}

// ---------------- K2: serial RNN scans (single-wave blocks, NO barriers) -----------
__global__ void k_rnn(const float* __restrict__ P,
                      const float* __restrict__ W_lr, const float* __restrict__ W_rl,
                      const float* __restrict__ h0, __bf16* __restrict__ hcat) {
    __shared__ float Psh[S * 4 * HID];   // 16 KB: [s][bl][j]
    __shared__ float hsh[4][17];
    const int t = threadIdx.x;
    const int dir = blockIdx.x >> 3, bq = blockIdx.x & 7;
    const int bl = t >> 4, j = t & 15;
    const int b = bq * 4 + bl;
    {
        const float4* Pg4 = reinterpret_cast<const float4*>(P);
        float4* Ps4 = reinterpret_cast<float4*>(Psh);
        #pragma unroll
        for (int i = 0; i < 16; ++i) {
            int s = (t >> 4) + 4 * i;
            Ps4[t + 64 * i] = Pg4[dir * 8192 + s * 128 + bq * 16 + (t & 15)];
        }
    }
    const float* Wd = (dir ? W_rl : W_lr) + j * (EMB + HID) + EMB;
    float wh[16];
    #pragma unroll
    for (int q = 0; q < 4; ++q) {
        float4 w4 = *reinterpret_cast<const float4*>(Wd + q * 4);
        wh[q * 4 + 0] = w4.x; wh[q * 4 + 1] = w4.y;
        wh[q * 4 + 2] = w4.z; wh[q * 4 + 3] = w4.w;
    }
    float hcur = h0[j];
    hsh[bl][j] = hcur;
    for (int step = 0; step < S; ++step) {
        const int s = dir ? (S - 1 - step) : step;
        hcat[(s * B + b) * 32 + dir * HID + j] = (__bf16)hcur;   // pre-state
        float acc = Psh[s * 64 + bl * 16 + j];
        #pragma unroll
        for (int k = 0; k < HID; ++k) acc += wh[k] * hsh[bl][k];
        hcur = tanhf(acc);
        hsh[bl][j] = hcur;
    }
}

// ---------------- K3: pass 1 — Wb slice in registers, loop over row-tiles ----------
__global__ void k_pass1(const __bf16* __restrict__ hb, const __bf16* __restrict__ Wb,
                        const float* __restrict__ bias, float* __restrict__ partials) {
    const int cbx = blockIdx.x, rg = blockIdx.y;
    const int wave = threadIdx.x >> 6, lane = threadIdx.x & 63;
    const int lr = lane & 15, kg = lane >> 4;
    const int ttbase = cbx * 16 + wave * 4;
    bf16x8 wfrag[4]; float bc[4];
    #pragma unroll
    for (int q = 0; q < 4; ++q) {
        wfrag[q] = *reinterpret_cast<const bf16x8*>(Wb + ((ttbase + q) * 16 + lr) * 32 + kg * 8);
        bc[q] = bias[(ttbase + q) * 16 + lr];
    }
    __shared__ float red[4][16];
    const f32x4 zero = {0.f, 0.f, 0.f, 0.f};
    for (int rt = rg * RT_PER; rt < rg * RT_PER + RT_PER; ++rt) {
        const int m0 = rt * 16;
        const bf16x8 a = *reinterpret_cast<const bf16x8*>(hb + (m0 + lr) * 32 + kg * 8);
        float s0 = 0.f, s1 = 0.f, s2 = 0.f, s3 = 0.f;
        #pragma unroll
        for (int q = 0; q < 4; ++q) {
            f32x4 d = __builtin_amdgcn_mfma_f32_16x16x32_bf16(a, wfrag[q], zero, 0, 0, 0);
            s0 += __expf(d[0] + bc[q]);
            s1 += __expf(d[1] + bc[q]);
            s2 += __expf(d[2] + bc[q]);
            s3 += __expf(d[3] + bc[q]);
        }
        #pragma unroll
        for (int off = 1; off < 16; off <<= 1) {
            s0 += __shfl_xor(s0, off);
            s1 += __shfl_xor(s1, off);
            s2 += __shfl_xor(s2, off);
            s3 += __shfl_xor(s3, off);
        }
        if (lr == 0) {
            red[wave][kg * 4 + 0] = s0;
            red[wave][kg * 4 + 1] = s1;
            red[wave][kg * 4 + 2] = s2;
            red[wave][kg * 4 + 3] = s3;
        }
        __syncthreads();
        if (threadIdx.x < 16)
            partials[cbx * M + m0 + threadIdx.x] =
                red[0][threadIdx.x] + red[1][threadIdx.x] +
                red[2][threadIdx.x] + red[3][threadIdx.x];
        __syncthreads();
    }
}

// ---------------- K4: reduce partials -> logZ per row ------------------------------
__global__ void k_reduce(const float* __restrict__ partials, float* __restrict__ logZ) {
    int r = blockIdx.x * 256 + threadIdx.x;
    float tot = 0.f;
    for (int c = 0; c < NCB; ++c) tot += partials[c * M + r];
    logZ[r] = logf(tot);
}

// ---------------- K5: pass 2 — lockstep linear write sweep + dwordx4 stores --------
// grid: 197 blocks (1 per CU). All blocks iterate rt together -> device writes one
// contiguous 16-row band (3.2 MB) at a time, sweeping the 412 MB output linearly.
__global__ void k_pass2(const __bf16* __restrict__ hb, const __bf16* __restrict__ Wb,
                        const float* __restrict__ bias, const float* __restrict__ logZ,
                        float* __restrict__ out) {
    __shared__ float stage[16][260];   // kg-stride 1040B%128 -> 2-way on write (free)
    const int cbx = blockIdx.x;
    const int wave = threadIdx.x >> 6, lane = threadIdx.x & 63;
    const int lr = lane & 15, kg = lane >> 4;
    const int ttbase = cbx * 16 + wave * 4;
    bf16x8 wfrag[4]; float bc[4];
    #pragma unroll
    for (int q = 0; q < 4; ++q) {
        wfrag[q] = *reinterpret_cast<const bf16x8*>(Wb + ((ttbase + q) * 16 + lr) * 32 + kg * 8);
        bc[q] = bias[(ttbase + q) * 16 + lr];
    }
    const int cb = cbx * 256;
    const bool full = (cb + 256 <= V);    // all but cbx==196
    const f32x4 zero = {0.f, 0.f, 0.f, 0.f};
    for (int rt = 0; rt < 128; ++rt) {
        const int m0 = rt * 16;
        const bf16x8 a = *reinterpret_cast<const bf16x8*>(hb + (m0 + lr) * 32 + kg * 8);
        #pragma unroll
        for (int q = 0; q < 4; ++q) {
            f32x4 d = __builtin_amdgcn_mfma_f32_16x16x32_bf16(a, wfrag[q], zero, 0, 0, 0);
            const int cl = wave * 64 + q * 16 + lr;
            #pragma unroll
            for (int r = 0; r < 4; ++r)
                stage[kg * 4 + r][cl] = d[r] + bc[q];
        }
        asm volatile("s_waitcnt lgkmcnt(0)" ::: "memory");
        __builtin_amdgcn_s_barrier();
        __builtin_amdgcn_sched_barrier(0);
        // write phase: wave w owns rows w*4..w*4+3. Alignment is compile-time per r:
        // (m*V+cb) mod 4 == r&3 (V%4==1, m0%4==0, cb%4==0) -> head h = (4-r)&3.
        #pragma unroll
        for (int r = 0; r < 4; ++r) {
            const int row = wave * 4 + r;
            const int m = m0 + row;
            const float lz = logZ[m];
            float* rp = out + (size_t)m * V + cb;
            if (full) {
                const int h = (4 - (r & 3)) & 3;      // 0,3,2,1
                const int k = h ? 63 : 64;
                if (lane < k) {
                    const int c = h + 4 * lane;
                    float4 v = { stage[row][c]     - lz, stage[row][c + 1] - lz,
                                 stage[row][c + 2] - lz, stage[row][c + 3] - lz };
                    *reinterpret_cast<float4*>(rp + c) = v;   // 16B-aligned dwordx4
                } else if (h) {                        // lane 63: head + tail scalars
                    #pragma unroll
                    for (int c = 0; c < h; ++c) rp[c] = stage[row][c] - lz;
                    #pragma unroll
                    for (int c = 0; c < 4 - h; ++c) {
                        const int cc = 256 - (4 - h) + c;
                        rp[cc] = stage[row][cc] - lz;
                    }
                }
            } else {                                   // last block: guarded scalars
                #pragma unroll
                for (int it = 0; it < 4; ++it) {
                    const int c = it * 64 + lane;
                    if (cb + c < V) rp[c] = stage[row][c] - lz;
                }
            }
        }
        asm volatile("s_waitcnt lgkmcnt(0)" ::: "memory");
        __builtin_amdgcn_s_barrier();
        __builtin_amdgcn_sched_barrier(0);
    }
}

extern "C" void kernel_launch(void* const* d_in, const int* in_sizes, int n_in,
                              void* d_out, int out_size, void* d_ws, size_t ws_size,
                              hipStream_t stream) {
    const int*   idx       = (const int*)d_in[0];
    const float* embedding = (const float*)d_in[1];
    const float* W_lr      = (const float*)d_in[2];
    const float* b_lr      = (const float*)d_in[3];
    const float* W_rl      = (const float*)d_in[4];
    const float* b_rl      = (const float*)d_in[5];
    const float* W_ho      = (const float*)d_in[6];
    const float* b_ho      = (const float*)d_in[7];
    const float* h0        = (const float*)d_in[8];
    float* out = (float*)d_out;

    char* ws = (char*)d_ws;
    size_t off = 0;
    __bf16* Wb      = (__bf16*)(ws + off); off += (size_t)VP2 * EMB * 2;   // 3,227,648
    float*  bias    = (float*)(ws + off);  off += (size_t)VP2 * 4;         //   201,728
    __bf16* hb      = (__bf16*)(ws + off); off += (size_t)M * 32 * 2;      //   131,072
    float*  P       = (float*)(ws + off);  off += (size_t)2 * M * HID * 4; //   262,144
    float*  partials= (float*)(ws + off);  off += (size_t)NCB * M * 4;     // 1,613,824
    float*  logZ    = (float*)(ws + off);  off += (size_t)M * 4;           //     8,192

    k_prep<<<PREP_BLOCKS + 256, 256, 0, stream>>>(W_ho, b_ho, idx, embedding,
                                                  W_lr, b_lr, W_rl, b_rl, Wb, bias, P);
    k_rnn<<<16, 64, 0, stream>>>(P, W_lr, W_rl, h0, hb);
    k_pass1<<<dim3(NCB, NRG), 256, 0, stream>>>(hb, Wb, bias, partials);
    k_reduce<<<8, 256, 0, stream>>>(partials, logZ);
    k_pass2<<<NCB, 256, 0, stream>>>(hb, Wb, bias, logZ, out);
}

// Round 6
// 208.016 us; speedup vs baseline: 1.5005x; 1.4090x over previous
//
#include <hip/hip_runtime.h>
#include <hip/hip_bf16.h>

#define S 64
#define B 32
#define HID 16
#define EMB 32
#define V 50257
#define NCB 197                 // column blocks of 256 cols
#define VP2 (NCB*256)           // 50432 padded cols
#define M 2048                  // S*B rows
#define PREP_BLOCKS (VP2*EMB/256)   // 6304 exactly
#define NRG 4                   // row groups for pass1
#define RT_PER (128/NRG)
#define NRG2 8                  // row groups for pass2
#define RT2 (128/NRG2)          // 16 row-tiles per pass2 block

using bf16x8 = __attribute__((ext_vector_type(8))) __bf16;
using f32x4  = __attribute__((ext_vector_type(4))) float;

// ---------------- K1: fused prep ---------------------------------------------------
__global__ void k_prep(const float* __restrict__ W_ho, const float* __restrict__ b_ho,
                       const int* __restrict__ idx, const float* __restrict__ emb,
                       const float* __restrict__ W_lr, const float* __restrict__ b_lr,
                       const float* __restrict__ W_rl, const float* __restrict__ b_rl,
                       __bf16* __restrict__ Wb, float* __restrict__ bias,
                       float* __restrict__ P) {
    const int bx = blockIdx.x;
    if (bx < PREP_BLOCKS) {
        int i = bx * 256 + threadIdx.x;          // < VP2*EMB exactly
        if (i < VP2) bias[i] = (i < V) ? b_ho[i] : -1e30f;
        int v = i >> 5;
        Wb[i] = (v < V) ? (__bf16)W_ho[i] : (__bf16)0.f;
    } else {
        int i = (bx - PREP_BLOCKS) * 256 + threadIdx.x;   // 0..65535
        const int dir = i >> 15, r = i & 32767, m = r >> 4, j = r & 15;
        const float* W  = dir ? W_rl : W_lr;
        const float* bb = dir ? b_rl : b_lr;
        const int tok = idx[m];
        const float4* er = reinterpret_cast<const float4*>(emb + (size_t)tok * EMB);
        const float4* wr = reinterpret_cast<const float4*>(W + j * (EMB + HID));
        float acc = bb[j];
        #pragma unroll
        for (int q = 0; q < 8; ++q) {
            float4 e4 = er[q], w4 = wr[q];
            acc += e4.x * w4.x + e4.y * w4.y + e4.z * w4.z + e4.w * w4.w;
        }
        P[i] = acc;
    }
}

// ---------------- K2: serial RNN scans (single-wave blocks, NO barriers) -----------
__global__ void k_rnn(const float* __restrict__ P,
                      const float* __restrict__ W_lr, const float* __restrict__ W_rl,
                      const float* __restrict__ h0, __bf16* __restrict__ hcat) {
    __shared__ float Psh[S * 4 * HID];   // 16 KB: [s][bl][j]
    __shared__ float hsh[4][17];
    const int t = threadIdx.x;
    const int dir = blockIdx.x >> 3, bq = blockIdx.x & 7;
    const int bl = t >> 4, j = t & 15;
    const int b = bq * 4 + bl;
    {
        const float4* Pg4 = reinterpret_cast<const float4*>(P);
        float4* Ps4 = reinterpret_cast<float4*>(Psh);
        #pragma unroll
        for (int i = 0; i < 16; ++i) {
            int s = (t >> 4) + 4 * i;
            Ps4[t + 64 * i] = Pg4[dir * 8192 + s * 128 + bq * 16 + (t & 15)];
        }
    }
    const float* Wd = (dir ? W_rl : W_lr) + j * (EMB + HID) + EMB;
    float wh[16];
    #pragma unroll
    for (int q = 0; q < 4; ++q) {
        float4 w4 = *reinterpret_cast<const float4*>(Wd + q * 4);
        wh[q * 4 + 0] = w4.x; wh[q * 4 + 1] = w4.y;
        wh[q * 4 + 2] = w4.z; wh[q * 4 + 3] = w4.w;
    }
    float hcur = h0[j];
    hsh[bl][j] = hcur;
    for (int step = 0; step < S; ++step) {
        const int s = dir ? (S - 1 - step) : step;
        hcat[(s * B + b) * 32 + dir * HID + j] = (__bf16)hcur;   // pre-state
        float acc = Psh[s * 64 + bl * 16 + j];
        #pragma unroll
        for (int k = 0; k < HID; ++k) acc += wh[k] * hsh[bl][k];
        hcur = tanhf(acc);
        hsh[bl][j] = hcur;
    }
}

// ---------------- K3: pass 1 — Wb slice in registers, loop over row-tiles ----------
__global__ void k_pass1(const __bf16* __restrict__ hb, const __bf16* __restrict__ Wb,
                        const float* __restrict__ bias, float* __restrict__ partials) {
    const int cbx = blockIdx.x, rg = blockIdx.y;
    const int wave = threadIdx.x >> 6, lane = threadIdx.x & 63;
    const int lr = lane & 15, kg = lane >> 4;
    const int ttbase = cbx * 16 + wave * 4;
    bf16x8 wfrag[4]; float bc[4];
    #pragma unroll
    for (int q = 0; q < 4; ++q) {
        wfrag[q] = *reinterpret_cast<const bf16x8*>(Wb + ((ttbase + q) * 16 + lr) * 32 + kg * 8);
        bc[q] = bias[(ttbase + q) * 16 + lr];
    }
    __shared__ float red[4][16];
    const f32x4 zero = {0.f, 0.f, 0.f, 0.f};
    for (int rt = rg * RT_PER; rt < rg * RT_PER + RT_PER; ++rt) {
        const int m0 = rt * 16;
        const bf16x8 a = *reinterpret_cast<const bf16x8*>(hb + (m0 + lr) * 32 + kg * 8);
        float s0 = 0.f, s1 = 0.f, s2 = 0.f, s3 = 0.f;
        #pragma unroll
        for (int q = 0; q < 4; ++q) {
            f32x4 d = __builtin_amdgcn_mfma_f32_16x16x32_bf16(a, wfrag[q], zero, 0, 0, 0);
            s0 += __expf(d[0] + bc[q]);
            s1 += __expf(d[1] + bc[q]);
            s2 += __expf(d[2] + bc[q]);
            s3 += __expf(d[3] + bc[q]);
        }
        #pragma unroll
        for (int off = 1; off < 16; off <<= 1) {
            s0 += __shfl_xor(s0, off);
            s1 += __shfl_xor(s1, off);
            s2 += __shfl_xor(s2, off);
            s3 += __shfl_xor(s3, off);
        }
        if (lr == 0) {
            red[wave][kg * 4 + 0] = s0;
            red[wave][kg * 4 + 1] = s1;
            red[wave][kg * 4 + 2] = s2;
            red[wave][kg * 4 + 3] = s3;
        }
        __syncthreads();
        if (threadIdx.x < 16)
            partials[cbx * M + m0 + threadIdx.x] =
                red[0][threadIdx.x] + red[1][threadIdx.x] +
                red[2][threadIdx.x] + red[3][threadIdx.x];
        __syncthreads();
    }
}

// ---------------- K4: reduce partials -> logZ per row ------------------------------
__global__ void k_reduce(const float* __restrict__ partials, float* __restrict__ logZ) {
    int r = blockIdx.x * 256 + threadIdx.x;
    float tot = 0.f;
    for (int c = 0; c < NCB; ++c) tot += partials[c * M + r];
    logZ[r] = logf(tot);
}

// ---------------- K5: pass 2 — barrier-free streaming: wave-private transpose ------
// grid: (NCB, NRG2) = 1576 blocks, 4 independent waves each. Wave owns 64 cols;
// transposes its own 4 MFMA tiles through a private LDS slab (no __syncthreads),
// then writes 16 rows x 256B contiguous. No vmcnt drain -> deep store pipeline.
__global__ void k_pass2(const __bf16* __restrict__ hb, const __bf16* __restrict__ Wb,
                        const float* __restrict__ bias, const float* __restrict__ logZ,
                        float* __restrict__ out) {
    __shared__ float stage[4][16][68];   // per-wave slab; 68: 2-way banks only (free)
    const int cbx = blockIdx.x, rg = blockIdx.y;
    const int wave = threadIdx.x >> 6, lane = threadIdx.x & 63;
    const int lr = lane & 15, kg = lane >> 4;
    const int ttbase = cbx * 16 + wave * 4;
    bf16x8 wfrag[4]; float bc[4];
    #pragma unroll
    for (int q = 0; q < 4; ++q) {
        wfrag[q] = *reinterpret_cast<const bf16x8*>(Wb + ((ttbase + q) * 16 + lr) * 32 + kg * 8);
        bc[q] = bias[(ttbase + q) * 16 + lr];
    }
    float (*st)[68] = stage[wave];
    const int cb0 = cbx * 256 + wave * 64;      // this wave's column base
    const int nv = V - cb0;                     // valid cols in this wave's span
    const f32x4 zero = {0.f, 0.f, 0.f, 0.f};
    for (int rt = rg * RT2; rt < rg * RT2 + RT2; ++rt) {
        const int m0 = rt * 16;
        const bf16x8 a = *reinterpret_cast<const bf16x8*>(hb + (m0 + lr) * 32 + kg * 8);
        #pragma unroll
        for (int q = 0; q < 4; ++q) {
            f32x4 d = __builtin_amdgcn_mfma_f32_16x16x32_bf16(a, wfrag[q], zero, 0, 0, 0);
            const int cl = q * 16 + lr;
            #pragma unroll
            for (int r = 0; r < 4; ++r)
                st[kg * 4 + r][cl] = d[r] + bc[q];
        }
        // wave-internal LDS fence: all ds_writes visible before cross-lane ds_reads
        asm volatile("s_waitcnt lgkmcnt(0)" ::: "memory");
        __builtin_amdgcn_sched_barrier(0);
        #pragma unroll
        for (int r = 0; r < 16; ++r) {
            const int m = m0 + r;
            const float lz = logZ[m];
            if (lane < nv)                       // uniform for all full waves
                out[(size_t)m * V + cb0 + lane] = st[r][lane] - lz;
        }
        asm volatile("s_waitcnt lgkmcnt(0)" ::: "memory");
        __builtin_amdgcn_sched_barrier(0);
    }
}

extern "C" void kernel_launch(void* const* d_in, const int* in_sizes, int n_in,
                              void* d_out, int out_size, void* d_ws, size_t ws_size,
                              hipStream_t stream) {
    const int*   idx       = (const int*)d_in[0];
    const float* embedding = (const float*)d_in[1];
    const float* W_lr      = (const float*)d_in[2];
    const float* b_lr      = (const float*)d_in[3];
    const float* W_rl      = (const float*)d_in[4];
    const float* b_rl      = (const float*)d_in[5];
    const float* W_ho      = (const float*)d_in[6];
    const float* b_ho      = (const float*)d_in[7];
    const float* h0        = (const float*)d_in[8];
    float* out = (float*)d_out;

    char* ws = (char*)d_ws;
    size_t off = 0;
    __bf16* Wb      = (__bf16*)(ws + off); off += (size_t)VP2 * EMB * 2;   // 3,227,648
    float*  bias    = (float*)(ws + off);  off += (size_t)VP2 * 4;         //   201,728
    __bf16* hb      = (__bf16*)(ws + off); off += (size_t)M * 32 * 2;      //   131,072
    float*  P       = (float*)(ws + off);  off += (size_t)2 * M * HID * 4; //   262,144
    float*  partials= (float*)(ws + off);  off += (size_t)NCB * M * 4;     // 1,613,824
    float*  logZ    = (float*)(ws + off);  off += (size_t)M * 4;           //     8,192

    k_prep<<<PREP_BLOCKS + 256, 256, 0, stream>>>(W_ho, b_ho, idx, embedding,
                                                  W_lr, b_lr, W_rl, b_rl, Wb, bias, P);
    k_rnn<<<16, 64, 0, stream>>>(P, W_lr, W_rl, h0, hb);
    k_pass1<<<dim3(NCB, NRG), 256, 0, stream>>>(hb, Wb, bias, partials);
    k_reduce<<<8, 256, 0, stream>>>(partials, logZ);
    k_pass2<<<dim3(NCB, NRG2), 256, 0, stream>>>(hb, Wb, bias, logZ, out);
}

// Round 7
// 187.789 us; speedup vs baseline: 1.6621x; 1.1077x over previous
//
#include <hip/hip_runtime.h>
#include <hip/hip_bf16.h>

#define S 64
#define B 32
#define HID 16
#define EMB 32
#define V 50257
#define NCB 197                 // pass1 column blocks of 256 cols (50432 scanned)
#define NCH 99                  // pass2 column chunks of 512 cols
#define VP3 (NCH*512)           // 50688 padded cols (Wb/bias allocation)
#define M 2048                  // S*B rows
#define PREP_BLOCKS (VP3*EMB/256)   // 6336 exactly
#define NRG 4                   // row groups for pass1
#define RT_PER (128/NRG)

using bf16x8 = __attribute__((ext_vector_type(8))) __bf16;
using f32x4  = __attribute__((ext_vector_type(4))) float;

// ---------------- K1: fused prep ---------------------------------------------------
__global__ void k_prep(const float* __restrict__ W_ho, const float* __restrict__ b_ho,
                       const int* __restrict__ idx, const float* __restrict__ emb,
                       const float* __restrict__ W_lr, const float* __restrict__ b_lr,
                       const float* __restrict__ W_rl, const float* __restrict__ b_rl,
                       __bf16* __restrict__ Wb, float* __restrict__ bias,
                       float* __restrict__ P) {
    const int bx = blockIdx.x;
    if (bx < PREP_BLOCKS) {
        int i = bx * 256 + threadIdx.x;          // < VP3*EMB exactly
        if (i < VP3) bias[i] = (i < V) ? b_ho[i] : -1e30f;
        int v = i >> 5;
        Wb[i] = (v < V) ? (__bf16)W_ho[i] : (__bf16)0.f;
    } else {
        int i = (bx - PREP_BLOCKS) * 256 + threadIdx.x;   // 0..65535
        const int dir = i >> 15, r = i & 32767, m = r >> 4, j = r & 15;
        const float* W  = dir ? W_rl : W_lr;
        const float* bb = dir ? b_rl : b_lr;
        const int tok = idx[m];
        const float4* er = reinterpret_cast<const float4*>(emb + (size_t)tok * EMB);
        const float4* wr = reinterpret_cast<const float4*>(W + j * (EMB + HID));
        float acc = bb[j];
        #pragma unroll
        for (int q = 0; q < 8; ++q) {
            float4 e4 = er[q], w4 = wr[q];
            acc += e4.x * w4.x + e4.y * w4.y + e4.z * w4.z + e4.w * w4.w;
        }
        P[i] = acc;
    }
}

// ---------------- K2: serial RNN scans (single-wave blocks, NO barriers) -----------
__global__ void k_rnn(const float* __restrict__ P,
                      const float* __restrict__ W_lr, const float* __restrict__ W_rl,
                      const float* __restrict__ h0, __bf16* __restrict__ hcat) {
    __shared__ float Psh[S * 4 * HID];   // 16 KB: [s][bl][j]
    __shared__ float hsh[4][17];
    const int t = threadIdx.x;
    const int dir = blockIdx.x >> 3, bq = blockIdx.x & 7;
    const int bl = t >> 4, j = t & 15;
    const int b = bq * 4 + bl;
    {
        const float4* Pg4 = reinterpret_cast<const float4*>(P);
        float4* Ps4 = reinterpret_cast<float4*>(Psh);
        #pragma unroll
        for (int i = 0; i < 16; ++i) {
            int s = (t >> 4) + 4 * i;
            Ps4[t + 64 * i] = Pg4[dir * 8192 + s * 128 + bq * 16 + (t & 15)];
        }
    }
    const float* Wd = (dir ? W_rl : W_lr) + j * (EMB + HID) + EMB;
    float wh[16];
    #pragma unroll
    for (int q = 0; q < 4; ++q) {
        float4 w4 = *reinterpret_cast<const float4*>(Wd + q * 4);
        wh[q * 4 + 0] = w4.x; wh[q * 4 + 1] = w4.y;
        wh[q * 4 + 2] = w4.z; wh[q * 4 + 3] = w4.w;
    }
    float hcur = h0[j];
    hsh[bl][j] = hcur;
    for (int step = 0; step < S; ++step) {
        const int s = dir ? (S - 1 - step) : step;
        hcat[(s * B + b) * 32 + dir * HID + j] = (__bf16)hcur;   // pre-state
        float acc = Psh[s * 64 + bl * 16 + j];
        #pragma unroll
        for (int k = 0; k < HID; ++k) acc += wh[k] * hsh[bl][k];
        hcur = tanhf(acc);
        hsh[bl][j] = hcur;
    }
}

// ---------------- K3: pass 1 — Wb slice in registers, loop over row-tiles ----------
__global__ void k_pass1(const __bf16* __restrict__ hb, const __bf16* __restrict__ Wb,
                        const float* __restrict__ bias, float* __restrict__ partials) {
    const int cbx = blockIdx.x, rg = blockIdx.y;
    const int wave = threadIdx.x >> 6, lane = threadIdx.x & 63;
    const int lr = lane & 15, kg = lane >> 4;
    const int ttbase = cbx * 16 + wave * 4;
    bf16x8 wfrag[4]; float bc[4];
    #pragma unroll
    for (int q = 0; q < 4; ++q) {
        wfrag[q] = *reinterpret_cast<const bf16x8*>(Wb + ((ttbase + q) * 16 + lr) * 32 + kg * 8);
        bc[q] = bias[(ttbase + q) * 16 + lr];
    }
    __shared__ float red[4][16];
    const f32x4 zero = {0.f, 0.f, 0.f, 0.f};
    for (int rt = rg * RT_PER; rt < rg * RT_PER + RT_PER; ++rt) {
        const int m0 = rt * 16;
        const bf16x8 a = *reinterpret_cast<const bf16x8*>(hb + (m0 + lr) * 32 + kg * 8);
        float s0 = 0.f, s1 = 0.f, s2 = 0.f, s3 = 0.f;
        #pragma unroll
        for (int q = 0; q < 4; ++q) {
            f32x4 d = __builtin_amdgcn_mfma_f32_16x16x32_bf16(a, wfrag[q], zero, 0, 0, 0);
            s0 += __expf(d[0] + bc[q]);
            s1 += __expf(d[1] + bc[q]);
            s2 += __expf(d[2] + bc[q]);
            s3 += __expf(d[3] + bc[q]);
        }
        #pragma unroll
        for (int off = 1; off < 16; off <<= 1) {
            s0 += __shfl_xor(s0, off);
            s1 += __shfl_xor(s1, off);
            s2 += __shfl_xor(s2, off);
            s3 += __shfl_xor(s3, off);
        }
        if (lr == 0) {
            red[wave][kg * 4 + 0] = s0;
            red[wave][kg * 4 + 1] = s1;
            red[wave][kg * 4 + 2] = s2;
            red[wave][kg * 4 + 3] = s3;
        }
        __syncthreads();
        if (threadIdx.x < 16)
            partials[cbx * M + m0 + threadIdx.x] =
                red[0][threadIdx.x] + red[1][threadIdx.x] +
                red[2][threadIdx.x] + red[3][threadIdx.x];
        __syncthreads();
    }
}

// ---------------- K4: reduce partials -> logZ per row ------------------------------
__global__ void k_reduce(const float* __restrict__ partials, float* __restrict__ logZ) {
    int r = blockIdx.x * 256 + threadIdx.x;
    float tot = 0.f;
    for (int c = 0; c < NCB; ++c) tot += partials[c * M + r];
    logZ[r] = logf(tot);
}

// ---------------- K5: pass 2 — row-stationary column sweep (linear row streams) ----
// grid: 256 x 512 threads. block = (row-tile bx>>1, column half bx&1). Each block
// owns 16 rows and sweeps 512-col chunks left->right: every output row is a strictly
// LINEAR write cursor (2 KB per visit). A-frag + logZ loaded once; Wb streams from L2.
__global__ __launch_bounds__(512) void k_pass2(
        const __bf16* __restrict__ hb, const __bf16* __restrict__ Wb,
        const float* __restrict__ bias, const float* __restrict__ logZ,
        float* __restrict__ out) {
    __shared__ float st[16][516];  // stage-write stride 516: kg offset 16 mod 32 -> 2-way
    const int bx = blockIdx.x;
    const int rt = bx >> 1, half = bx & 1;
    const int wave = threadIdx.x >> 6, lane = threadIdx.x & 63;
    const int lr = lane & 15, kg = lane >> 4;
    const int m0 = rt * 16;
    const bf16x8 a = *reinterpret_cast<const bf16x8*>(hb + (m0 + lr) * 32 + kg * 8);
    const int r0 = 2 * wave, r1 = r0 + 1;
    const float lz0 = logZ[m0 + r0], lz1 = logZ[m0 + r1];
    float* const row0 = out + (size_t)(m0 + r0) * V;
    float* const row1 = out + (size_t)(m0 + r1) * V;
    const f32x4 zero = {0.f, 0.f, 0.f, 0.f};
    const int ch0 = half ? 50 : 0, ch1 = half ? NCH : 50;
    for (int ch = ch0; ch < ch1; ++ch) {
        const int t0 = ch * 32 + wave * 4;           // this wave's first col-tile
        #pragma unroll
        for (int q = 0; q < 4; ++q) {
            const int tt = t0 + q;
            bf16x8 bf = *reinterpret_cast<const bf16x8*>(Wb + (tt * 16 + lr) * 32 + kg * 8);
            float bc = bias[tt * 16 + lr];
            f32x4 d = __builtin_amdgcn_mfma_f32_16x16x32_bf16(a, bf, zero, 0, 0, 0);
            const int cl = (wave * 4 + q) * 16 + lr;
            #pragma unroll
            for (int r = 0; r < 4; ++r)
                st[kg * 4 + r][cl] = d[r] + bc;
        }
        // barrier WITHOUT vmcnt drain: prior chunks' stores stay in flight
        asm volatile("s_waitcnt lgkmcnt(0)" ::: "memory");
        __builtin_amdgcn_s_barrier();
        __builtin_amdgcn_sched_barrier(0);
        const int cb = ch * 512;
        if (cb + 512 <= V) {                          // ch 0..97: all cols valid
            #pragma unroll
            for (int it = 0; it < 8; ++it) {
                const int c = it * 64 + lane;
                row0[cb + c] = st[r0][c] - lz0;
            }
            #pragma unroll
            for (int it = 0; it < 8; ++it) {
                const int c = it * 64 + lane;
                row1[cb + c] = st[r1][c] - lz1;
            }
        } else {                                      // ch 98: 81 valid cols
            #pragma unroll
            for (int it = 0; it < 8; ++it) {
                const int c = it * 64 + lane;
                if (cb + c < V) row0[cb + c] = st[r0][c] - lz0;
            }
            #pragma unroll
            for (int it = 0; it < 8; ++it) {
                const int c = it * 64 + lane;
                if (cb + c < V) row1[cb + c] = st[r1][c] - lz1;
            }
        }
        asm volatile("s_waitcnt lgkmcnt(0)" ::: "memory");
        __builtin_amdgcn_s_barrier();
        __builtin_amdgcn_sched_barrier(0);
    }
}

extern "C" void kernel_launch(void* const* d_in, const int* in_sizes, int n_in,
                              void* d_out, int out_size, void* d_ws, size_t ws_size,
                              hipStream_t stream) {
    const int*   idx       = (const int*)d_in[0];
    const float* embedding = (const float*)d_in[1];
    const float* W_lr      = (const float*)d_in[2];
    const float* b_lr      = (const float*)d_in[3];
    const float* W_rl      = (const float*)d_in[4];
    const float* b_rl      = (const float*)d_in[5];
    const float* W_ho      = (const float*)d_in[6];
    const float* b_ho      = (const float*)d_in[7];
    const float* h0        = (const float*)d_in[8];
    float* out = (float*)d_out;

    char* ws = (char*)d_ws;
    size_t off = 0;
    __bf16* Wb      = (__bf16*)(ws + off); off += (size_t)VP3 * EMB * 2;   // 3,244,032
    float*  bias    = (float*)(ws + off);  off += (size_t)VP3 * 4;         //   202,752
    __bf16* hb      = (__bf16*)(ws + off); off += (size_t)M * 32 * 2;      //   131,072
    float*  P       = (float*)(ws + off);  off += (size_t)2 * M * HID * 4; //   262,144
    float*  partials= (float*)(ws + off);  off += (size_t)NCB * M * 4;     // 1,613,824
    float*  logZ    = (float*)(ws + off);  off += (size_t)M * 4;           //     8,192

    k_prep<<<PREP_BLOCKS + 256, 256, 0, stream>>>(W_ho, b_ho, idx, embedding,
                                                  W_lr, b_lr, W_rl, b_rl, Wb, bias, P);
    k_rnn<<<16, 64, 0, stream>>>(P, W_lr, W_rl, h0, hb);
    k_pass1<<<dim3(NCB, NRG), 256, 0, stream>>>(hb, Wb, bias, partials);
    k_reduce<<<8, 256, 0, stream>>>(partials, logZ);
    k_pass2<<<256, 512, 0, stream>>>(hb, Wb, bias, logZ, out);
}